// Round 1
// baseline (1334.056 us; speedup 1.0000x reference)
//
#include <hip/hip_runtime.h>
#include <hip/hip_bf16.h>
#include <stdint.h>

#define K_CODES 8192
#define DDIM    256
#define NTOK    32768   // B*H*W = 8*64*64
#define HW      4096    // 64*64

typedef float f32x4 __attribute__((ext_vector_type(4)));
typedef short bf16x8 __attribute__((ext_vector_type(8)));  // 8 bf16 = 4 VGPRs

__device__ __forceinline__ unsigned short f2bf(float f) {
  union { float f; unsigned u; } v; v.f = f;
  unsigned r = (v.u + 0x7fffu + ((v.u >> 16) & 1u)) >> 16;
  return (unsigned short)r;
}

// ---------------------------------------------------------------------------
// Kernel A: transpose z_e_x [B,D,HW] -> Xb bf16 [N, D] (token-major), + x_sqr
// Block = 64 tokens (one b), 256 threads.
// ---------------------------------------------------------------------------
__global__ __launch_bounds__(256) void k_xpose(const float* __restrict__ z,
                                               unsigned short* __restrict__ Xb,
                                               float* __restrict__ xs) {
  __shared__ unsigned short T[DDIM * 64];  // [d][tok], 32 KB
  __shared__ float xsp[256];
  const int t = threadIdx.x;
  const int n0 = blockIdx.x * 64;
  const int b = n0 >> 12, hw0 = n0 & 4095;
  const int tok = t & 63, dq = t >> 6;
  const float* src = z + ((size_t)b * DDIM) * HW + hw0 + tok;
  float s = 0.f;
#pragma unroll 8
  for (int d = dq * 64; d < dq * 64 + 64; ++d) {
    float v = src[(size_t)d * HW];   // coalesced: lanes = consecutive tok
    s += v * v;
    T[d * 64 + tok] = f2bf(v);       // contiguous 128B per instr: conflict-free
  }
  xsp[t] = s;
  __syncthreads();
  if (t < 64) xs[n0 + t] = xsp[t] + xsp[t + 64] + xsp[t + 128] + xsp[t + 192];
  // phase 2: write token-major rows (512 B each) as 16-B chunks
  const int tok2 = t >> 2, q = t & 3;
  uint32_t* dstbase = (uint32_t*)(Xb + (size_t)(n0 + tok2) * DDIM);
#pragma unroll
  for (int j = 0; j < 8; ++j) {
    int col16 = j * 4 + q;  // which 16-byte unit of the 512-B row (0..31)
    int d0 = col16 * 8;
    union { unsigned short u[8]; uint32_t w[4]; } pk;
#pragma unroll
    for (int e = 0; e < 8; ++e) pk.u[e] = T[(d0 + e) * 64 + tok2];
    uint4 o; o.x = pk.w[0]; o.y = pk.w[1]; o.z = pk.w[2]; o.w = pk.w[3];
    *(uint4*)(dstbase + col16 * 4) = o;
  }
}

// ---------------------------------------------------------------------------
// Kernel B: convert codebook -> bf16 + cb_sqr.  8 rows per block.
// ---------------------------------------------------------------------------
__global__ __launch_bounds__(256) void k_cb(const float* __restrict__ cb,
                                            unsigned short* __restrict__ Cbf,
                                            float* __restrict__ cs) {
  const int t = threadIdx.x;
  const size_t flat0 = (size_t)blockIdx.x * 2048 + (size_t)t * 8;
  f32x4 v0 = *(const f32x4*)(cb + flat0);
  f32x4 v1 = *(const f32x4*)(cb + flat0 + 4);
  float s = v0[0]*v0[0] + v0[1]*v0[1] + v0[2]*v0[2] + v0[3]*v0[3]
          + v1[0]*v1[0] + v1[1]*v1[1] + v1[2]*v1[2] + v1[3]*v1[3];
  union { unsigned short u[8]; uint4 w; } pk;
#pragma unroll
  for (int e = 0; e < 4; ++e) pk.u[e] = f2bf(v0[e]);
#pragma unroll
  for (int e = 0; e < 4; ++e) pk.u[4 + e] = f2bf(v1[e]);
  *(uint4*)(Cbf + flat0) = pk.w;
  // 32 threads per row -> shuffle-reduce within 32-lane groups
#pragma unroll
  for (int off = 1; off < 32; off <<= 1) s += __shfl_xor(s, off);
  if ((t & 31) == 0) cs[flat0 >> 8] = s;
}

// ---------------------------------------------------------------------------
// Kernel C: the GEMM. C[token][code] = X · CB^T via mfma 16x16x32 bf16.
// 128x128 tile, BK=64, 4 K-steps, global_load_lds width 16 (m97 structure).
// Epilogue: logits = 2*dot - xs - cs (nontemporal float4), packed-u64 argmin.
// ---------------------------------------------------------------------------
__global__ __launch_bounds__(256) void k_gemm(
    const unsigned short* __restrict__ Xb, const unsigned short* __restrict__ Cbf,
    const float* __restrict__ xs, const float* __restrict__ cs,
    float* __restrict__ out2, unsigned long long* __restrict__ minp) {
  __shared__ unsigned short As[128 * 64];  // [token][k] packed, 16 KB
  __shared__ unsigned short Bs[128 * 64];  // [code][k]  packed, 16 KB
  const int tid = threadIdx.x;
  const int l = tid & 63, w = tid >> 6;
  const int wm = w & 1, wn = w >> 1;      // 2x2 wave grid, each wave 64x64
  const int tok0 = blockIdx.y * 128, code0 = blockIdx.x * 128;
  f32x4 acc[4][4] = {};
  const char* gA = (const char*)Xb  + (size_t)(tok0  + (tid >> 3)) * 512 + (size_t)(tid & 7) * 16;
  const char* gB = (const char*)Cbf + (size_t)(code0 + (tid >> 3)) * 512 + (size_t)(tid & 7) * 16;

  for (int kc = 0; kc < 4; ++kc) {
#pragma unroll
    for (int c = 0; c < 4; ++c) {  // 32 rows per call (256 lanes x 16 B)
      __builtin_amdgcn_global_load_lds(
          (const __attribute__((address_space(1))) void*)(gA + (size_t)c * 32 * 512 + (size_t)kc * 128),
          (__attribute__((address_space(3))) void*)(&As[c * 2048 + w * 512]), 16, 0, 0);
      __builtin_amdgcn_global_load_lds(
          (const __attribute__((address_space(1))) void*)(gB + (size_t)c * 32 * 512 + (size_t)kc * 128),
          (__attribute__((address_space(3))) void*)(&Bs[c * 2048 + w * 512]), 16, 0, 0);
    }
    __syncthreads();
#pragma unroll
    for (int ks = 0; ks < 2; ++ks) {
      const int ko = ks * 32 + (l >> 4) * 8;
      bf16x8 a[4], b[4];
#pragma unroll
      for (int i = 0; i < 4; ++i)
        a[i] = *(const bf16x8*)&As[(wm * 64 + i * 16 + (l & 15)) * 64 + ko];
#pragma unroll
      for (int j = 0; j < 4; ++j)
        b[j] = *(const bf16x8*)&Bs[(wn * 64 + j * 16 + (l & 15)) * 64 + ko];
#pragma unroll
      for (int i = 0; i < 4; ++i)
#pragma unroll
        for (int j = 0; j < 4; ++j)
          acc[i][j] = __builtin_amdgcn_mfma_f32_16x16x32_bf16(a[i], b[j], acc[i][j], 0, 0, 0);
    }
    __syncthreads();
  }

  // Epilogue. C/D layout: col = lane&15 (code), row = (lane>>4)*4 + reg (token).
  const int col_l = l & 15, row_l = (l >> 4) * 4;
  const int b_img = tok0 >> 12, hwb = tok0 & 4095;
  float* outbase = out2 + ((size_t)b_img * K_CODES + code0 + wn * 64) * HW + hwb + wm * 64;
#pragma unroll
  for (int i = 0; i < 4; ++i) {
    const int trow = wm * 64 + i * 16 + row_l;            // token offset in tile
    f32x4 xs4 = *(const f32x4*)&xs[tok0 + trow];
    f32x4 bd; int bc0, bc1, bc2, bc3;
#pragma unroll
    for (int j = 0; j < 4; ++j) {
      const int code = code0 + wn * 64 + j * 16 + col_l;
      const float csj = cs[code];
      f32x4 dist, lg;
#pragma unroll
      for (int r = 0; r < 4; ++r) {
        dist[r] = xs4[r] + csj - 2.f * acc[i][j][r];
        lg[r] = -dist[r];
      }
      f32x4* dst = (f32x4*)(outbase + (size_t)(j * 16 + col_l) * HW + (i * 16 + row_l));
      __builtin_nontemporal_store(lg, dst);
      if (j == 0) { bd = dist; bc0 = bc1 = bc2 = bc3 = code; }
      else {
        if (dist[0] < bd[0]) { bd[0] = dist[0]; bc0 = code; }
        if (dist[1] < bd[1]) { bd[1] = dist[1]; bc1 = code; }
        if (dist[2] < bd[2]) { bd[2] = dist[2]; bc2 = code; }
        if (dist[3] < bd[3]) { bd[3] = dist[3]; bc3 = code; }
      }
    }
    int bcs[4] = {bc0, bc1, bc2, bc3};
#pragma unroll
    for (int r = 0; r < 4; ++r) {
      unsigned long long pk =
          ((unsigned long long)__float_as_uint(bd[r]) << 32) | (unsigned)bcs[r];
#pragma unroll
      for (int m = 1; m <= 8; m <<= 1) {  // reduce over the 16 lanes sharing a token
        unsigned long long o = __shfl_xor(pk, m);
        pk = o < pk ? o : pk;
      }
      if (col_l == 0) atomicMin(&minp[tok0 + trow + r], pk);
    }
  }
}

// ---------------------------------------------------------------------------
// Kernel D: gather codes -> z_q_x and z_q_x_bar (identical forward values).
// ---------------------------------------------------------------------------
__global__ __launch_bounds__(256) void k_gather(const unsigned long long* __restrict__ minp,
                                                const float* __restrict__ cb,
                                                float* __restrict__ o0) {
  const int t = threadIdx.x;
  const int n = blockIdx.x * 256 + t;
  const int b = n >> 12, hw = n & 4095;
  const unsigned code = (unsigned)(minp[n] & 0xffffffffull);
  const float* crow = cb + (size_t)code * DDIM;
  float* p0 = o0 + (size_t)b * DDIM * HW + hw;
  float* p1 = p0 + (size_t)NTOK * DDIM;
#pragma unroll 4
  for (int d = 0; d < DDIM; ++d) {
    float v = crow[d];
    p0[(size_t)d * HW] = v;  // coalesced over hw
    p1[(size_t)d * HW] = v;
  }
}

// ---------------------------------------------------------------------------
extern "C" void kernel_launch(void* const* d_in, const int* in_sizes, int n_in,
                              void* d_out, int out_size, void* d_ws, size_t ws_size,
                              hipStream_t stream) {
  const float* z  = (const float*)d_in[0];  // [8,256,64,64]
  const float* cb = (const float*)d_in[1];  // [8192,256]
  char* ws = (char*)d_ws;
  unsigned long long* minp = (unsigned long long*)ws;          // 32768 * 8 B
  float* xs          = (float*)(ws + 262144);                  // 32768 f32
  float* cs          = (float*)(ws + 393216);                  // 8192 f32
  unsigned short* Cbf = (unsigned short*)(ws + 425984);        // 8192*256 bf16
  unsigned short* Xb  = (unsigned short*)(ws + 4620288);       // 32768*256 bf16
  float* out = (float*)d_out;
  float* logits = out + 2 * (size_t)NTOK * DDIM;               // +16,777,216

  hipMemsetAsync(minp, 0xFF, (size_t)NTOK * 8, stream);        // +inf packed keys
  k_xpose<<<NTOK / 64, 256, 0, stream>>>(z, Xb, xs);
  k_cb<<<(K_CODES * DDIM) / 2048, 256, 0, stream>>>(cb, Cbf, cs);
  k_gemm<<<dim3(K_CODES / 128, NTOK / 128), 256, 0, stream>>>(Xb, Cbf, xs, cs, logits, minp);
  k_gather<<<NTOK / 256, 256, 0, stream>>>(minp, cb, out);
}